// Round 3
// baseline (1532.862 us; speedup 1.0000x reference)
//
#include <hip/hip_runtime.h>
#include <math.h>

#define TPC 225
#define NCLS 224
#define NHID 1024
#define BATCH 2048
#define CAP 256      // bucket capacity per class (mean ~9.1)
#define LSTRIDE 256  // logits ws row stride (floats)
#define NCHUNK 8     // d-chunks per row
#define CHUNK_D 128  // NHID / NCHUNK
#define NDQ 32       // CHUNK_D / 4

// ---------------------------------------------------------------------------
// Kernel 1: bucket examples by class. Single block, LDS atomics.
// ---------------------------------------------------------------------------
__global__ __launch_bounds__(256) void hs_bucket(const int* __restrict__ labels,
                                                 int* __restrict__ bucket,
                                                 int* __restrict__ cnt) {
    __shared__ int scnt[NCLS];
    const int t = threadIdx.x;
    for (int i = t; i < NCLS; i += 256) scnt[i] = 0;
    __syncthreads();
    for (int b = t; b < BATCH; b += 256) {
        int lab = labels[b];
        int c = lab / TPC;
        int pos = atomicAdd(&scnt[c], 1);
        bucket[c * CAP + pos] = b;
    }
    __syncthreads();
    for (int i = t; i < NCLS; i += 256) cnt[i] = scnt[i];
}

// ---------------------------------------------------------------------------
// Generic 128-d chunk GEMM: RW rows x KS cols, k = lane + 64j (j<4, clamped).
// Register double-buffer kept (cheap); latency hiding primarily via TLP
// (7-8 blocks/CU resident).
// ---------------------------------------------------------------------------
#define LOADW(W)                                              \
    do {                                                      \
        _Pragma("unroll") for (int di = 0; di < 4; di++)      \
            _Pragma("unroll") for (int j = 0; j < 4; j++)     \
                W[di][j] = pj[j][di * KS];                    \
        _Pragma("unroll") for (int j = 0; j < 4; j++)         \
            pj[j] += 4 * KS;                                  \
    } while (0)

#define LOADX(X, dq)                                          \
    do {                                                      \
        _Pragma("unroll") for (int rl = 0; rl < RW; rl++)     \
            X[rl] = *(const float4*)(xp[rl] + (dq) * 4);      \
    } while (0)

#define FMAS(W, X)                                            \
    do {                                                      \
        _Pragma("unroll") for (int rl = 0; rl < RW; rl++) {   \
            _Pragma("unroll") for (int di = 0; di < 4; di++) {\
                float xv = ((const float*)&X[rl])[di];        \
                _Pragma("unroll") for (int j = 0; j < 4; j++) \
                    acc[rl][j] = fmaf(xv, W[di][j], acc[rl][j]); \
            }                                                 \
        }                                                     \
    } while (0)

template <int RW, int KS>
__device__ __forceinline__ void gemm_chunk(const float* __restrict__ xb,
                                           const int* rows,
                                           const float* __restrict__ wq,
                                           const int lane,
                                           float acc[RW][4]) {
    const float* xp[RW];
#pragma unroll
    for (int rl = 0; rl < RW; rl++) xp[rl] = xb + (size_t)rows[rl] * NHID;
    const float* pj[4];
#pragma unroll
    for (int j = 0; j < 4; j++) {
        int k = 64 * j + lane;
        pj[j] = wq + (k < KS ? k : KS - 1);
    }
#pragma unroll
    for (int rl = 0; rl < RW; rl++)
#pragma unroll
        for (int j = 0; j < 4; j++) acc[rl][j] = 0.f;

    float wA[4][4], wB[4][4];
    float4 xA[RW], xB[RW];
    LOADW(wA);
    LOADX(xA, 0);
    for (int dq = 0; dq < NDQ; dq += 2) {
        LOADW(wB);                  // prefetch dq+1 weights
        LOADX(xB, dq + 1);
        FMAS(wA, xA);               // compute dq
        if (dq + 2 < NDQ) {
            LOADW(wA);              // prefetch dq+2
            LOADX(xA, dq + 2);
        }
        FMAS(wB, xB);               // compute dq+1
    }
}

// ---------------------------------------------------------------------------
// Kernel 2: top logits. Grid = 256 row-blocks x 8 d-chunks = 2048 blocks
// (8/CU), 256 threads = 4 waves = 4 row-groups of 2 rows. Barrier-free;
// 8 partial buffers summed in hs_finish.
// ---------------------------------------------------------------------------
__global__ __launch_bounds__(256, 8) void hs_tlogits(const float* __restrict__ x,
                                                     const float* __restrict__ W,
                                                     float* __restrict__ twsP) {
    const int rb = blockIdx.x >> 3;  // row-block 0..255
    const int q = blockIdx.x & 7;    // d-chunk 0..7
    const int lane = threadIdx.x & 63;
    const int wr = threadIdx.x >> 6;  // row-group 0..3
    int rows[2] = {rb * 8 + wr * 2, rb * 8 + wr * 2 + 1};
    const float* xb = x + q * CHUNK_D;
    const float* wq = W + (size_t)q * CHUNK_D * NCLS;
    float acc[2][4];
    gemm_chunk<2, NCLS>(xb, rows, wq, lane, acc);
    float* tp = twsP + (size_t)q * BATCH * LSTRIDE;
#pragma unroll
    for (int rl = 0; rl < 2; rl++)
#pragma unroll
        for (int j = 0; j < 4; j++) {
            int k = 64 * j + lane;
            if (k < NCLS) tp[(size_t)rows[rl] * LSTRIDE + k] = acc[rl][j];
        }
}

// ---------------------------------------------------------------------------
// Kernel 3: bottom logits. Grid = 224 classes x 8 d-chunks = 1792 blocks
// (7/CU exactly), 256 threads = 4 waves = 4 row-groups. Barrier-free;
// 8 partial buffers summed in hs_finish.
// ---------------------------------------------------------------------------
template <int RW>
__device__ __forceinline__ void bchunk(const float* __restrict__ xb,
                                       const float* __restrict__ wq,
                                       const int* __restrict__ bucket_c,
                                       const int base, const int n,
                                       const int lane, const int wr,
                                       float* __restrict__ bp) {
    int rows[RW], rval[RW];
#pragma unroll
    for (int rl = 0; rl < RW; rl++) {
        int idx = base + wr * RW + rl;
        rows[rl] = bucket_c[idx < n ? idx : 0];  // pad rows alias entry 0
        rval[rl] = (idx < n);
    }
    float acc[RW][4];
    gemm_chunk<RW, TPC>(xb, rows, wq, lane, acc);
#pragma unroll
    for (int rl = 0; rl < RW; rl++) {
        if (rval[rl]) {
#pragma unroll
            for (int j = 0; j < 4; j++) {
                int k = 64 * j + lane;
                if (k < TPC) bp[(size_t)rows[rl] * LSTRIDE + k] = acc[rl][j];
            }
        }
    }
}

__global__ __launch_bounds__(256, 7) void hs_blogits(const float* __restrict__ x,
                                                     const float* __restrict__ Wb,
                                                     const int* __restrict__ bucket,
                                                     const int* __restrict__ cnt,
                                                     float* __restrict__ bws) {
    const int c = blockIdx.x >> 3;  // class
    const int q = blockIdx.x & 7;   // d-chunk
    const int n = cnt[c];
    if (n == 0) return;
    const int lane = threadIdx.x & 63;
    const int wr = threadIdx.x >> 6;  // row-group 0..3
    const float* wq = Wb + (size_t)c * (NHID * TPC) + (size_t)q * CHUNK_D * TPC;
    const float* xb = x + q * CHUNK_D;
    const int* bucket_c = bucket + c * CAP;
    float* bp = bws + (size_t)q * BATCH * LSTRIDE;

    for (int base = 0; base < n; base += 16) {
        int m = n - base;
        if (m > 16) m = 16;
        const int RW = (m + 3) >> 2;
        switch (RW) {  // block-uniform
            case 1: bchunk<1>(xb, wq, bucket_c, base, n, lane, wr, bp); break;
            case 2: bchunk<2>(xb, wq, bucket_c, base, n, lane, wr, bp); break;
            case 3: bchunk<3>(xb, wq, bucket_c, base, n, lane, wr, bp); break;
            default: bchunk<4>(xb, wq, bucket_c, base, n, lane, wr, bp); break;
        }
    }
}

// ---------------------------------------------------------------------------
// Kernel 4: finish. One wave per row: sum 8 d-chunk partials, softmax over
// top (224) and bottom (225) logits (bias added here), out = p_cls * p_word.
// ---------------------------------------------------------------------------
__global__ __launch_bounds__(256) void hs_finish(const float* __restrict__ tws,
                                                 const float* __restrict__ bws,
                                                 const int* __restrict__ labels,
                                                 const float* __restrict__ b_top,
                                                 const float* __restrict__ b_bot,
                                                 float* __restrict__ out) {
    const int lane = threadIdx.x & 63;
    const int wave = threadIdx.x >> 6;
    const int row = blockIdx.x * 4 + wave;
    const int label = labels[row];
    const int c = label / TPC;
    const int word = label - c * TPC;

    float p[2];
#pragma unroll
    for (int lvl = 0; lvl < 2; lvl++) {
        const int NS = lvl ? TPC : NCLS;
        const int pick = lvl ? word : c;
        const float* lws = lvl ? bws : tws;
        const float* bias = lvl ? (b_bot + c * TPC) : b_top;
        float lg[4];
#pragma unroll
        for (int j = 0; j < 4; j++) {
            int k = lane + 64 * j;
            if (k < NS) {
                float v = 0.f;
#pragma unroll
                for (int pq = 0; pq < NCHUNK; pq++)
                    v += lws[((size_t)pq * BATCH + row) * LSTRIDE + k];
                lg[j] = v + bias[k];
            } else {
                lg[j] = -INFINITY;
            }
        }
        float m = fmaxf(fmaxf(lg[0], lg[1]), fmaxf(lg[2], lg[3]));
#pragma unroll
        for (int off = 32; off > 0; off >>= 1) m = fmaxf(m, __shfl_xor(m, off, 64));
        float s = 0.f, pp = 0.f;
#pragma unroll
        for (int j = 0; j < 4; j++) {
            int k = lane + 64 * j;
            float e = (k < NS) ? __expf(lg[j] - m) : 0.f;
            s += e;
            if (k == pick) pp = e;
        }
#pragma unroll
        for (int off = 32; off > 0; off >>= 1) {
            s += __shfl_xor(s, off, 64);
            pp += __shfl_xor(pp, off, 64);
        }
        p[lvl] = pp / s;
    }
    if (lane == 0) out[row] = p[0] * p[1];
}

// ---------------------------------------------------------------------------
extern "C" void kernel_launch(void* const* d_in, const int* in_sizes, int n_in,
                              void* d_out, int out_size, void* d_ws, size_t ws_size,
                              hipStream_t stream) {
    const float* inputs   = (const float*)d_in[0];
    const int*   labels   = (const int*)d_in[1];
    const float* W_top    = (const float*)d_in[2];
    const float* b_top    = (const float*)d_in[3];
    const float* W_bottom = (const float*)d_in[4];
    const float* b_bottom = (const float*)d_in[5];
    float* out = (float*)d_out;

    // ws: bucket[NCLS*CAP] | cnt[NCLS] | tws[8*B*LSTRIDE] | bws[8*B*LSTRIDE]
    int* bucket = (int*)d_ws;
    int* cnt    = bucket + NCLS * CAP;
    float* tws  = (float*)(cnt + NCLS);
    float* bws  = tws + (size_t)NCHUNK * BATCH * LSTRIDE;

    hs_bucket<<<1, 256, 0, stream>>>(labels, bucket, cnt);
    hs_tlogits<<<256 * NCHUNK, 256, 0, stream>>>(inputs, W_top, tws);
    hs_blogits<<<NCLS * NCHUNK, 256, 0, stream>>>(inputs, W_bottom, bucket, cnt, bws);
    hs_finish<<<BATCH / 4, 256, 0, stream>>>(tws, bws, labels, b_top, b_bottom, out);
}

// Round 4
// 409.913 us; speedup vs baseline: 3.7395x; 3.7395x over previous
//
#include <hip/hip_runtime.h>
#include <math.h>

#define TPC 225
#define NCLS 224
#define NHID 1024
#define BATCH 2048
#define CAP 256      // bucket capacity per class (mean ~9.1)
#define LSTRIDE 256  // logits ws row stride (floats)
#define NCHUNK 8     // d-chunks per row
#define CHUNK_D 128  // NHID / NCHUNK
#define NDQ 32       // CHUNK_D / 4

// ---------------------------------------------------------------------------
// Kernel 1: bucket examples by class. Single block, LDS atomics.
// ---------------------------------------------------------------------------
__global__ __launch_bounds__(256) void hs_bucket(const int* __restrict__ labels,
                                                 int* __restrict__ bucket,
                                                 int* __restrict__ cnt) {
    __shared__ int scnt[NCLS];
    const int t = threadIdx.x;
    for (int i = t; i < NCLS; i += 256) scnt[i] = 0;
    __syncthreads();
    for (int b = t; b < BATCH; b += 256) {
        int lab = labels[b];
        int c = lab / TPC;
        int pos = atomicAdd(&scnt[c], 1);
        bucket[c * CAP + pos] = b;
    }
    __syncthreads();
    for (int i = t; i < NCLS; i += 256) cnt[i] = scnt[i];
}

// ---------------------------------------------------------------------------
// Generic 128-d chunk GEMM: RW rows x KS cols, k = lane + 64j (j<4, clamped).
// EXACT Round-2 inner body (proven 64 VGPR / no spill under (256,4)).
// Latency hiding via TLP: 7-8 blocks/CU resident at 64 VGPR.
// ---------------------------------------------------------------------------
#define LOADW(W)                                              \
    do {                                                      \
        _Pragma("unroll") for (int di = 0; di < 4; di++)      \
            _Pragma("unroll") for (int j = 0; j < 4; j++)     \
                W[di][j] = pj[j][di * KS];                    \
        _Pragma("unroll") for (int j = 0; j < 4; j++)         \
            pj[j] += 4 * KS;                                  \
    } while (0)

#define LOADX(X, dq)                                          \
    do {                                                      \
        _Pragma("unroll") for (int rl = 0; rl < RW; rl++)     \
            X[rl] = *(const float4*)(xp[rl] + (dq) * 4);      \
    } while (0)

#define FMAS(W, X)                                            \
    do {                                                      \
        _Pragma("unroll") for (int rl = 0; rl < RW; rl++) {   \
            _Pragma("unroll") for (int di = 0; di < 4; di++) {\
                float xv = ((const float*)&X[rl])[di];        \
                _Pragma("unroll") for (int j = 0; j < 4; j++) \
                    acc[rl][j] = fmaf(xv, W[di][j], acc[rl][j]); \
            }                                                 \
        }                                                     \
    } while (0)

template <int RW, int KS>
__device__ __forceinline__ void gemm_chunk(const float* __restrict__ xb,
                                           const int* rows,
                                           const float* __restrict__ wq,
                                           const int lane,
                                           float acc[RW][4]) {
    const float* xp[RW];
#pragma unroll
    for (int rl = 0; rl < RW; rl++) xp[rl] = xb + (size_t)rows[rl] * NHID;
    const float* pj[4];
#pragma unroll
    for (int j = 0; j < 4; j++) {
        int k = 64 * j + lane;
        pj[j] = wq + (k < KS ? k : KS - 1);
    }
#pragma unroll
    for (int rl = 0; rl < RW; rl++)
#pragma unroll
        for (int j = 0; j < 4; j++) acc[rl][j] = 0.f;

    float wA[4][4], wB[4][4];
    float4 xA[RW], xB[RW];
    LOADW(wA);
    LOADX(xA, 0);
    for (int dq = 0; dq < NDQ; dq += 2) {
        LOADW(wB);                  // prefetch dq+1 weights
        LOADX(xB, dq + 1);
        FMAS(wA, xA);               // compute dq
        if (dq + 2 < NDQ) {
            LOADW(wA);              // prefetch dq+2
            LOADX(xA, dq + 2);
        }
        FMAS(wB, xB);               // compute dq+1
    }
}

// ---------------------------------------------------------------------------
// Kernel 2: top logits. Grid = 256 row-blocks x 8 d-chunks = 2048 blocks
// (8/CU), 256 threads = 4 waves = 4 row-groups of 2 rows. Barrier-free;
// 8 partial buffers summed in hs_finish. NOTE (256,4): min-waves 7/8 forces
// the <=64-VGPR bin and catastrophic scratch spill (R3: WRITE_SIZE 1.3 GB).
// ---------------------------------------------------------------------------
__global__ __launch_bounds__(256, 4) void hs_tlogits(const float* __restrict__ x,
                                                     const float* __restrict__ W,
                                                     float* __restrict__ twsP) {
    const int rb = blockIdx.x >> 3;  // row-block 0..255
    const int q = blockIdx.x & 7;    // d-chunk 0..7
    const int lane = threadIdx.x & 63;
    const int wr = threadIdx.x >> 6;  // row-group 0..3
    int rows[2] = {rb * 8 + wr * 2, rb * 8 + wr * 2 + 1};
    const float* xb = x + q * CHUNK_D;
    const float* wq = W + (size_t)q * CHUNK_D * NCLS;
    float acc[2][4];
    gemm_chunk<2, NCLS>(xb, rows, wq, lane, acc);
    float* tp = twsP + (size_t)q * BATCH * LSTRIDE;
#pragma unroll
    for (int rl = 0; rl < 2; rl++)
#pragma unroll
        for (int j = 0; j < 4; j++) {
            int k = 64 * j + lane;
            if (k < NCLS) tp[(size_t)rows[rl] * LSTRIDE + k] = acc[rl][j];
        }
}

// ---------------------------------------------------------------------------
// Kernel 3: bottom logits. Grid = 224 classes x 8 d-chunks = 1792 blocks
// (7/CU), 256 threads = 4 waves = 4 row-groups. Barrier-free; 8 partial
// buffers summed in hs_finish.
// ---------------------------------------------------------------------------
template <int RW>
__device__ __forceinline__ void bchunk(const float* __restrict__ xb,
                                       const float* __restrict__ wq,
                                       const int* __restrict__ bucket_c,
                                       const int base, const int n,
                                       const int lane, const int wr,
                                       float* __restrict__ bp) {
    int rows[RW], rval[RW];
#pragma unroll
    for (int rl = 0; rl < RW; rl++) {
        int idx = base + wr * RW + rl;
        rows[rl] = bucket_c[idx < n ? idx : 0];  // pad rows alias entry 0
        rval[rl] = (idx < n);
    }
    float acc[RW][4];
    gemm_chunk<RW, TPC>(xb, rows, wq, lane, acc);
#pragma unroll
    for (int rl = 0; rl < RW; rl++) {
        if (rval[rl]) {
#pragma unroll
            for (int j = 0; j < 4; j++) {
                int k = 64 * j + lane;
                if (k < TPC) bp[(size_t)rows[rl] * LSTRIDE + k] = acc[rl][j];
            }
        }
    }
}

__global__ __launch_bounds__(256, 4) void hs_blogits(const float* __restrict__ x,
                                                     const float* __restrict__ Wb,
                                                     const int* __restrict__ bucket,
                                                     const int* __restrict__ cnt,
                                                     float* __restrict__ bws) {
    const int c = blockIdx.x >> 3;  // class
    const int q = blockIdx.x & 7;   // d-chunk
    const int n = cnt[c];
    if (n == 0) return;
    const int lane = threadIdx.x & 63;
    const int wr = threadIdx.x >> 6;  // row-group 0..3
    const float* wq = Wb + (size_t)c * (NHID * TPC) + (size_t)q * CHUNK_D * TPC;
    const float* xb = x + q * CHUNK_D;
    const int* bucket_c = bucket + c * CAP;
    float* bp = bws + (size_t)q * BATCH * LSTRIDE;

    for (int base = 0; base < n; base += 16) {
        int m = n - base;
        if (m > 16) m = 16;
        const int RW = (m + 3) >> 2;
        switch (RW) {  // block-uniform
            case 1: bchunk<1>(xb, wq, bucket_c, base, n, lane, wr, bp); break;
            case 2: bchunk<2>(xb, wq, bucket_c, base, n, lane, wr, bp); break;
            case 3: bchunk<3>(xb, wq, bucket_c, base, n, lane, wr, bp); break;
            default: bchunk<4>(xb, wq, bucket_c, base, n, lane, wr, bp); break;
        }
    }
}

// ---------------------------------------------------------------------------
// Kernel 4: finish. One wave per row: sum 8 d-chunk partials, softmax over
// top (224) and bottom (225) logits (bias added here), out = p_cls * p_word.
// ---------------------------------------------------------------------------
__global__ __launch_bounds__(256) void hs_finish(const float* __restrict__ tws,
                                                 const float* __restrict__ bws,
                                                 const int* __restrict__ labels,
                                                 const float* __restrict__ b_top,
                                                 const float* __restrict__ b_bot,
                                                 float* __restrict__ out) {
    const int lane = threadIdx.x & 63;
    const int wave = threadIdx.x >> 6;
    const int row = blockIdx.x * 4 + wave;
    const int label = labels[row];
    const int c = label / TPC;
    const int word = label - c * TPC;

    float p[2];
#pragma unroll
    for (int lvl = 0; lvl < 2; lvl++) {
        const int NS = lvl ? TPC : NCLS;
        const int pick = lvl ? word : c;
        const float* lws = lvl ? bws : tws;
        const float* bias = lvl ? (b_bot + c * TPC) : b_top;
        float lg[4];
#pragma unroll
        for (int j = 0; j < 4; j++) {
            int k = lane + 64 * j;
            if (k < NS) {
                float v = 0.f;
#pragma unroll
                for (int pq = 0; pq < NCHUNK; pq++)
                    v += lws[((size_t)pq * BATCH + row) * LSTRIDE + k];
                lg[j] = v + bias[k];
            } else {
                lg[j] = -INFINITY;
            }
        }
        float m = fmaxf(fmaxf(lg[0], lg[1]), fmaxf(lg[2], lg[3]));
#pragma unroll
        for (int off = 32; off > 0; off >>= 1) m = fmaxf(m, __shfl_xor(m, off, 64));
        float s = 0.f, pp = 0.f;
#pragma unroll
        for (int j = 0; j < 4; j++) {
            int k = lane + 64 * j;
            float e = (k < NS) ? __expf(lg[j] - m) : 0.f;
            s += e;
            if (k == pick) pp = e;
        }
#pragma unroll
        for (int off = 32; off > 0; off >>= 1) {
            s += __shfl_xor(s, off, 64);
            pp += __shfl_xor(pp, off, 64);
        }
        p[lvl] = pp / s;
    }
    if (lane == 0) out[row] = p[0] * p[1];
}

// ---------------------------------------------------------------------------
extern "C" void kernel_launch(void* const* d_in, const int* in_sizes, int n_in,
                              void* d_out, int out_size, void* d_ws, size_t ws_size,
                              hipStream_t stream) {
    const float* inputs   = (const float*)d_in[0];
    const int*   labels   = (const int*)d_in[1];
    const float* W_top    = (const float*)d_in[2];
    const float* b_top    = (const float*)d_in[3];
    const float* W_bottom = (const float*)d_in[4];
    const float* b_bottom = (const float*)d_in[5];
    float* out = (float*)d_out;

    // ws: bucket[NCLS*CAP] | cnt[NCLS] | tws[8*B*LSTRIDE] | bws[8*B*LSTRIDE]
    int* bucket = (int*)d_ws;
    int* cnt    = bucket + NCLS * CAP;
    float* tws  = (float*)(cnt + NCLS);
    float* bws  = tws + (size_t)NCHUNK * BATCH * LSTRIDE;

    hs_bucket<<<1, 256, 0, stream>>>(labels, bucket, cnt);
    hs_tlogits<<<256 * NCHUNK, 256, 0, stream>>>(inputs, W_top, tws);
    hs_blogits<<<NCLS * NCHUNK, 256, 0, stream>>>(inputs, W_bottom, bucket, cnt, bws);
    hs_finish<<<BATCH / 4, 256, 0, stream>>>(tws, bws, labels, b_top, b_bottom, out);
}